// Round 2
// baseline (151.192 us; speedup 1.0000x reference)
//
#include <hip/hip_runtime.h>

#define B_ROWS 1048576
#define NTHREADS2 (B_ROWS / 2)   // main kernel: 2 rows per thread

__device__ __forceinline__ float fast_tanh(float x) {
    // tanh(x) = 1 - 2/(exp(2x)+1); exp2 via v_exp_f32
    float e = __builtin_amdgcn_exp2f(x * 2.8853900817779268f);
    return 1.0f - 2.0f * __builtin_amdgcn_rcpf(e + 1.0f);
}

__device__ __forceinline__ float fast_sigmoid(float x) {
    float e = __builtin_amdgcn_exp2f(x * -1.4426950408889634f); // exp(-x)
    return __builtin_amdgcn_rcpf(1.0f + e);
}

// ---------------- pass 1: per-feature sum / sumsq over all rows ----------------
__global__ __launch_bounds__(256) void bn_stats(const float* __restrict__ x,
                                                float* __restrict__ ws) {
    const int tid = blockIdx.x * 256 + threadIdx.x;   // 0..65535 (256 blocks)
    float s[8], q[8];
#pragma unroll
    for (int c = 0; c < 8; ++c) { s[c] = 0.f; q[c] = 0.f; }
    const float4* x4 = (const float4*)x;
#pragma unroll 4
    for (int k = 0; k < 16; ++k) {
        int r = tid + k * 65536;
        float4 a = x4[2 * r];
        float4 b = x4[2 * r + 1];
        s[0] += a.x; s[1] += a.y; s[2] += a.z; s[3] += a.w;
        s[4] += b.x; s[5] += b.y; s[6] += b.z; s[7] += b.w;
        q[0] += a.x * a.x; q[1] += a.y * a.y; q[2] += a.z * a.z; q[3] += a.w * a.w;
        q[4] += b.x * b.x; q[5] += b.y * b.y; q[6] += b.z * b.z; q[7] += b.w * b.w;
    }
    // wave(64) shuffle reduction
#pragma unroll
    for (int off = 32; off > 0; off >>= 1) {
#pragma unroll
        for (int c = 0; c < 8; ++c) {
            s[c] += __shfl_down(s[c], off);
            q[c] += __shfl_down(q[c], off);
        }
    }
    __shared__ float red[4][16];
    const int lane = threadIdx.x & 63;
    const int wave = threadIdx.x >> 6;
    if (lane == 0) {
#pragma unroll
        for (int c = 0; c < 8; ++c) { red[wave][c] = s[c]; red[wave][8 + c] = q[c]; }
    }
    __syncthreads();
    if (threadIdx.x < 16) {
        float acc = red[0][threadIdx.x] + red[1][threadIdx.x] +
                    red[2][threadIdx.x] + red[3][threadIdx.x];
        atomicAdd(&ws[threadIdx.x], acc);
    }
}

// ---------------- fused 2-row linear layer (weights stay uniform -> SGPR) ------
template<int DIN, int DOUT>
__device__ __forceinline__ void linear2(const float* __restrict__ a, const float* __restrict__ b,
                                        float* __restrict__ oa, float* __restrict__ ob,
                                        const float* __restrict__ w, const float* __restrict__ bias) {
#pragma unroll
    for (int j = 0; j < DOUT; ++j) { float t = bias[j]; oa[j] = t; ob[j] = t; }
#pragma unroll
    for (int i = 0; i < DIN; ++i) {
        float ai = a[i], bi = b[i];
#pragma unroll
        for (int j = 0; j < DOUT; ++j) {
            float ww = w[i * DOUT + j];     // uniform address -> s_load, SGPR operand
            oa[j] = fmaf(ai, ww, oa[j]);
            ob[j] = fmaf(bi, ww, ob[j]);
        }
    }
}

template<int N>
__device__ __forceinline__ void tanh2(float* a, float* b) {
#pragma unroll
    for (int j = 0; j < N; ++j) { a[j] = fast_tanh(a[j]); b[j] = fast_tanh(b[j]); }
}

// ---------------- pass 2: normalize + MLP chain, 2 rows/thread -----------------
__global__ __launch_bounds__(256) void qcnn_main(
    const float* __restrict__ x,
    const float* __restrict__ bn_g, const float* __restrict__ bn_b,
    const float* __restrict__ w_fm, const float* __restrict__ b_fm,
    const float* __restrict__ w_c1, const float* __restrict__ b_c1,
    const float* __restrict__ w_p1, const float* __restrict__ b_p1,
    const float* __restrict__ w_c2, const float* __restrict__ b_c2,
    const float* __restrict__ w_p2, const float* __restrict__ b_p2,
    const float* __restrict__ w_c3, const float* __restrict__ b_c3,
    const float* __restrict__ w_r,  const float* __restrict__ b_r,
    const float* __restrict__ w_h,  const float* __restrict__ b_h,
    const float* __restrict__ ws, float* __restrict__ out)
{
    const float invB = 1.0f / (float)B_ROWS;
    float scale[8], shift[8];
#pragma unroll
    for (int c = 0; c < 8; ++c) {
        float mu  = ws[c] * invB;
        float var = fmaf(-mu, mu, ws[8 + c] * invB);
        float sc  = bn_g[c] * rsqrtf(var + 1e-5f);
        scale[c] = sc;
        shift[c] = fmaf(-mu, sc, bn_b[c]);
    }

    const int tid = blockIdx.x * 256 + threadIdx.x;   // 0..524287
    const int r0 = tid, r1 = tid + NTHREADS2;
    const float4* x4 = (const float4*)x;
    float4 xa0 = x4[2 * r0], xa1 = x4[2 * r0 + 1];
    float4 xb0 = x4[2 * r1], xb1 = x4[2 * r1 + 1];

    float a8[8], b8[8];
    a8[0] = xa0.x; a8[1] = xa0.y; a8[2] = xa0.z; a8[3] = xa0.w;
    a8[4] = xa1.x; a8[5] = xa1.y; a8[6] = xa1.z; a8[7] = xa1.w;
    b8[0] = xb0.x; b8[1] = xb0.y; b8[2] = xb0.z; b8[3] = xb0.w;
    b8[4] = xb1.x; b8[5] = xb1.y; b8[6] = xb1.z; b8[7] = xb1.w;
#pragma unroll
    for (int c = 0; c < 8; ++c) {
        a8[c] = fmaf(a8[c], scale[c], shift[c]);
        b8[c] = fmaf(b8[c], scale[c], shift[c]);
    }

    float a16[16], b16[16];
    linear2<8, 16>(a8, b8, a16, b16, w_fm, b_fm);  tanh2<16>(a16, b16);
    float t16a[16], t16b[16];
    linear2<16, 16>(a16, b16, t16a, t16b, w_c1, b_c1);  tanh2<16>(t16a, t16b);
    float a12[12], b12[12];
    linear2<16, 12>(t16a, t16b, a12, b12, w_p1, b_p1);  tanh2<12>(a12, b12);
    float c8a[8], c8b[8];
    linear2<12, 8>(a12, b12, c8a, c8b, w_c2, b_c2);  tanh2<8>(c8a, c8b);
    float a4[4], b4[4];
    linear2<8, 4>(c8a, c8b, a4, b4, w_p2, b_p2);  tanh2<4>(a4, b4);
    float c4a[4], c4b[4];
    linear2<4, 4>(a4, b4, c4a, c4b, w_c3, b_c3);  tanh2<4>(c4a, c4b);
    float r4a[4], r4b[4];
    linear2<4, 4>(c4a, c4b, r4a, r4b, w_r, b_r);
#pragma unroll
    for (int j = 0; j < 4; ++j) {
        c4a[j] += fmaxf(r4a[j], 0.f);
        c4b[j] += fmaxf(r4b[j], 0.f);
    }
    float oa[1], ob[1];
    linear2<4, 1>(c4a, c4b, oa, ob, w_h, b_h);
    out[r0] = fast_sigmoid(oa[0]);
    out[r1] = fast_sigmoid(ob[0]);
}

extern "C" void kernel_launch(void* const* d_in, const int* in_sizes, int n_in,
                              void* d_out, int out_size, void* d_ws, size_t ws_size,
                              hipStream_t stream) {
    const float* x    = (const float*)d_in[0];
    const float* bn_g = (const float*)d_in[1];
    const float* bn_b = (const float*)d_in[2];
    const float* w_fm = (const float*)d_in[3];
    const float* b_fm = (const float*)d_in[4];
    const float* w_c1 = (const float*)d_in[5];
    const float* b_c1 = (const float*)d_in[6];
    const float* w_p1 = (const float*)d_in[7];
    const float* b_p1 = (const float*)d_in[8];
    const float* w_c2 = (const float*)d_in[9];
    const float* b_c2 = (const float*)d_in[10];
    const float* w_p2 = (const float*)d_in[11];
    const float* b_p2 = (const float*)d_in[12];
    const float* w_c3 = (const float*)d_in[13];
    const float* b_c3 = (const float*)d_in[14];
    const float* w_r  = (const float*)d_in[15];
    const float* b_r  = (const float*)d_in[16];
    const float* w_h  = (const float*)d_in[17];
    const float* b_h  = (const float*)d_in[18];
    float* out = (float*)d_out;
    float* ws  = (float*)d_ws;

    (void)hipMemsetAsync(d_ws, 0, 16 * sizeof(float), stream);
    bn_stats<<<256, 256, 0, stream>>>(x, ws);
    qcnn_main<<<B_ROWS / 512, 256, 0, stream>>>(
        x, bn_g, bn_b, w_fm, b_fm, w_c1, b_c1, w_p1, b_p1, w_c2, b_c2,
        w_p2, b_p2, w_c3, b_c3, w_r, b_r, w_h, b_h, ws, out);
}